// Round 1
// baseline (737.830 us; speedup 1.0000x reference)
//
#include <hip/hip_runtime.h>
#include <hip/hip_bf16.h>

#define NN 50000
#define NE 1600000
#define FEAT 128
#define NG 128
#define NC 10

constexpr int SCAN_BLOCKS = (NN + 255) / 256; // 196

// ---------------- degree + count ----------------
__global__ void k_deg_count(const int* __restrict__ col, const float* __restrict__ ew,
                            float* __restrict__ deg, int* __restrict__ counts) {
    int e = blockIdx.x * blockDim.x + threadIdx.x;
    if (e < NE) {
        int c = col[e];
        atomicAdd(&deg[c], ew[e]);
        atomicAdd(&counts[c], 1);
    }
}

__global__ void k_dinv(const float* __restrict__ deg, float* __restrict__ dinv) {
    int n = blockIdx.x * blockDim.x + threadIdx.x;
    if (n < NN) dinv[n] = rsqrtf(deg[n] + 1.0f); // +1 = self-loop weight; always > 0
}

// ---------------- exclusive scan of counts (3 tiny kernels) ----------------
__global__ void k_scanA(const int* __restrict__ counts, int* __restrict__ offsets,
                        int* __restrict__ blockSums) {
    __shared__ int tmp[256];
    int i = blockIdx.x * 256 + threadIdx.x;
    int v = (i < NN) ? counts[i] : 0;
    tmp[threadIdx.x] = v;
    __syncthreads();
    for (int off = 1; off < 256; off <<= 1) {
        int t = (threadIdx.x >= off) ? tmp[threadIdx.x - off] : 0;
        __syncthreads();
        tmp[threadIdx.x] += t;
        __syncthreads();
    }
    if (i < NN) offsets[i] = tmp[threadIdx.x] - v; // block-local exclusive
    if (threadIdx.x == 255) blockSums[blockIdx.x] = tmp[255];
}

__global__ void k_scanB(int* __restrict__ blockSums) {
    __shared__ int tmp[256];
    int t = threadIdx.x;
    int v = (t < SCAN_BLOCKS) ? blockSums[t] : 0;
    tmp[t] = v;
    __syncthreads();
    for (int off = 1; off < 256; off <<= 1) {
        int u = (t >= off) ? tmp[t - off] : 0;
        __syncthreads();
        tmp[t] += u;
        __syncthreads();
    }
    if (t < SCAN_BLOCKS) blockSums[t] = tmp[t] - v; // exclusive
}

__global__ void k_scanC(int* __restrict__ offsets, const int* __restrict__ blockSums,
                        int* __restrict__ cursor) {
    int i = blockIdx.x * 256 + threadIdx.x;
    if (i < NN) {
        int o = offsets[i] + blockSums[blockIdx.x];
        offsets[i] = o;
        cursor[i] = o;
    }
}

// ---------------- CSR fill ----------------
__global__ void k_fill(const int* __restrict__ row, const int* __restrict__ col,
                       const float* __restrict__ ew, const float* __restrict__ dinv,
                       int* __restrict__ cursor, int* __restrict__ csr_row,
                       float* __restrict__ csr_norm) {
    int e = blockIdx.x * blockDim.x + threadIdx.x;
    if (e < NE) {
        int r = row[e], c = col[e];
        float nrm = dinv[r] * ew[e] * dinv[c];
        int pos = atomicAdd(&cursor[c], 1);
        csr_row[pos] = r;
        csr_norm[pos] = nrm;
    }
}

// ---------------- fp32 GEMM: C[NN x 128] = A[NN x 128] @ W[128 x 128] ----------------
__global__ __launch_bounds__(256) void k_gemm(const float* __restrict__ A,
                                              const float* __restrict__ W,
                                              float* __restrict__ C) {
    __shared__ float As[64][33];   // padded: broadcast-read rows, stride 33 avoids conflicts
    __shared__ float Ws[32][128];
    const int row0 = blockIdx.x * 64;
    const int t = threadIdx.x;
    const int c4 = (t & 31) * 4;
    const int rg = t >> 5;
    float4 acc[8];
#pragma unroll
    for (int i = 0; i < 8; ++i) acc[i] = make_float4(0.f, 0.f, 0.f, 0.f);

    for (int k0 = 0; k0 < 128; k0 += 32) {
        // A panel: 64 rows x 32 k (512 float4)
#pragma unroll
        for (int l = 0; l < 2; ++l) {
            int q = t + l * 256;
            int r = q >> 3, kk4 = (q & 7) * 4;
            int grow = row0 + r;
            float4 v = make_float4(0.f, 0.f, 0.f, 0.f);
            if (grow < NN) v = *(const float4*)(A + (size_t)grow * 128 + k0 + kk4);
            As[r][kk4] = v.x; As[r][kk4 + 1] = v.y; As[r][kk4 + 2] = v.z; As[r][kk4 + 3] = v.w;
        }
        // W panel: 32 k x 128 cols (1024 float4)
#pragma unroll
        for (int l = 0; l < 4; ++l) {
            int q = t + l * 256;
            int kk = q >> 5, cc4 = (q & 31) * 4;
            *(float4*)(&Ws[kk][cc4]) = *(const float4*)(W + (size_t)(k0 + kk) * 128 + cc4);
        }
        __syncthreads();
#pragma unroll
        for (int kk = 0; kk < 32; ++kk) {
            float4 w4 = *(const float4*)(&Ws[kk][c4]);
#pragma unroll
            for (int i = 0; i < 8; ++i) {
                float a = As[rg + 8 * i][kk];
                acc[i].x += a * w4.x;
                acc[i].y += a * w4.y;
                acc[i].z += a * w4.z;
                acc[i].w += a * w4.w;
            }
        }
        __syncthreads();
    }
#pragma unroll
    for (int i = 0; i < 8; ++i) {
        int grow = row0 + rg + 8 * i;
        if (grow < NN) *(float4*)(C + (size_t)grow * 128 + c4) = acc[i];
    }
}

// ---------------- pull-style aggregation: one wave per node ----------------
// out[n] = relu( b + sum_{e: col=n} h[row_e]*norm_e + h[n]*dinv[n]^2 )
// POOL: atomicAdd result into pooled[batch[n]] instead of writing out.
template <bool POOL>
__global__ __launch_bounds__(256) void k_agg(const float* __restrict__ h,
                                             const int* __restrict__ offsets,
                                             const int* __restrict__ counts,
                                             const int* __restrict__ csr_row,
                                             const float* __restrict__ csr_norm,
                                             const float* __restrict__ dinv,
                                             const float* __restrict__ bias,
                                             const int* __restrict__ batch,
                                             float* __restrict__ out) {
    const int node = blockIdx.x * 4 + (threadIdx.x >> 6);
    if (node >= NN) return;
    const int lane = threadIdx.x & 63;

    float di = dinv[node];
    float sn = di * di;
    float2 hv = *(const float2*)(h + (size_t)node * 128 + lane * 2);
    float2 acc = make_float2(hv.x * sn, hv.y * sn);

    const int start = offsets[node];
    const int cnt = counts[node];
    const int* rp = csr_row + start;
    const float* wp = csr_norm + start;
    int j = 0;
    for (; j + 4 <= cnt; j += 4) {
        int r0 = rp[j], r1 = rp[j + 1], r2 = rp[j + 2], r3 = rp[j + 3];
        float n0 = wp[j], n1 = wp[j + 1], n2 = wp[j + 2], n3 = wp[j + 3];
        float2 v0 = *(const float2*)(h + (size_t)r0 * 128 + lane * 2);
        float2 v1 = *(const float2*)(h + (size_t)r1 * 128 + lane * 2);
        float2 v2 = *(const float2*)(h + (size_t)r2 * 128 + lane * 2);
        float2 v3 = *(const float2*)(h + (size_t)r3 * 128 + lane * 2);
        acc.x += v0.x * n0; acc.y += v0.y * n0;
        acc.x += v1.x * n1; acc.y += v1.y * n1;
        acc.x += v2.x * n2; acc.y += v2.y * n2;
        acc.x += v3.x * n3; acc.y += v3.y * n3;
    }
    for (; j < cnt; ++j) {
        int r = rp[j];
        float nw = wp[j];
        float2 v = *(const float2*)(h + (size_t)r * 128 + lane * 2);
        acc.x += v.x * nw; acc.y += v.y * nw;
    }

    float2 b2 = *(const float2*)(bias + lane * 2);
    acc.x = fmaxf(acc.x + b2.x, 0.f);
    acc.y = fmaxf(acc.y + b2.y, 0.f);

    if (POOL) {
        int g = batch[node];
        atomicAdd(&out[(size_t)g * 128 + lane * 2], acc.x);
        atomicAdd(&out[(size_t)g * 128 + lane * 2 + 1], acc.y);
    } else {
        *(float2*)(out + (size_t)node * 128 + lane * 2) = acc;
    }
}

// ---------------- FC + log_softmax: one wave per graph ----------------
__global__ __launch_bounds__(64) void k_fc(const float* __restrict__ pooled,
                                           const float* __restrict__ Wfc,
                                           const float* __restrict__ bfc,
                                           float* __restrict__ out) {
    const int g = blockIdx.x;
    const int lane = threadIdx.x;
    float p0 = pooled[(size_t)g * 128 + lane];
    float p1 = pooled[(size_t)g * 128 + 64 + lane];
    float logits[NC];
#pragma unroll
    for (int c = 0; c < NC; ++c) {
        float v = p0 * Wfc[lane * NC + c] + p1 * Wfc[(64 + lane) * NC + c];
#pragma unroll
        for (int off = 32; off > 0; off >>= 1) v += __shfl_down(v, off);
        logits[c] = v;
    }
    if (lane == 0) {
        float mx = -1e30f;
#pragma unroll
        for (int c = 0; c < NC; ++c) { logits[c] += bfc[c]; mx = fmaxf(mx, logits[c]); }
        float s = 0.f;
#pragma unroll
        for (int c = 0; c < NC; ++c) s += expf(logits[c] - mx);
        float lse = mx + logf(s);
#pragma unroll
        for (int c = 0; c < NC; ++c) out[(size_t)g * NC + c] = logits[c] - lse;
    }
}

extern "C" void kernel_launch(void* const* d_in, const int* in_sizes, int n_in,
                              void* d_out, int out_size, void* d_ws, size_t ws_size,
                              hipStream_t stream) {
    const float* x         = (const float*)d_in[0];
    const int*   edge_index= (const int*)d_in[1];
    const int*   batch     = (const int*)d_in[2];
    const float* edge_mask = (const float*)d_in[3];
    const float* W1        = (const float*)d_in[4];
    const float* b1        = (const float*)d_in[5];
    const float* W2        = (const float*)d_in[6];
    const float* b2        = (const float*)d_in[7];
    const float* Wfc       = (const float*)d_in[8];
    const float* bfc       = (const float*)d_in[9];
    float* out = (float*)d_out;

    const int* row = edge_index;        // edge_index[0]
    const int* col = edge_index + NE;   // edge_index[1]

    char* ws = (char*)d_ws;
    size_t off = 0;
    auto alloc = [&](size_t bytes) -> void* {
        off = (off + 255) & ~(size_t)255;
        void* p = ws + off;
        off += bytes;
        return p;
    };
    float* deg      = (float*)alloc((size_t)NN * 4);
    int*   counts   = (int*)  alloc((size_t)NN * 4);
    int*   offsets  = (int*)  alloc((size_t)NN * 4);
    int*   cursor   = (int*)  alloc((size_t)NN * 4);
    int*   blockSums= (int*)  alloc(256 * 4);
    float* dinv     = (float*)alloc((size_t)NN * 4);
    int*   csr_row  = (int*)  alloc((size_t)NE * 4);
    float* csr_norm = (float*)alloc((size_t)NE * 4);
    float* h_a      = (float*)alloc((size_t)NN * FEAT * 4);
    float* h_b      = (float*)alloc((size_t)NN * FEAT * 4);
    float* pooled   = (float*)alloc((size_t)NG * FEAT * 4);

    hipMemsetAsync(deg, 0, (size_t)NN * 4, stream);
    hipMemsetAsync(counts, 0, (size_t)NN * 4, stream);
    hipMemsetAsync(pooled, 0, (size_t)NG * FEAT * 4, stream);

    k_deg_count<<<(NE + 255) / 256, 256, 0, stream>>>(col, edge_mask, deg, counts);
    k_dinv<<<(NN + 255) / 256, 256, 0, stream>>>(deg, dinv);
    k_scanA<<<SCAN_BLOCKS, 256, 0, stream>>>(counts, offsets, blockSums);
    k_scanB<<<1, 256, 0, stream>>>(blockSums);
    k_scanC<<<SCAN_BLOCKS, 256, 0, stream>>>(offsets, blockSums, cursor);
    k_fill<<<(NE + 255) / 256, 256, 0, stream>>>(row, col, edge_mask, dinv, cursor,
                                                 csr_row, csr_norm);
    // layer 1: h_a = x @ W1 ; h_b = relu(agg(h_a) + b1)
    k_gemm<<<(NN + 63) / 64, 256, 0, stream>>>(x, W1, h_a);
    k_agg<false><<<(NN + 3) / 4, 256, 0, stream>>>(h_a, offsets, counts, csr_row, csr_norm,
                                                   dinv, b1, nullptr, h_b);
    // layer 2: h_a = h_b @ W2 ; pooled += relu(agg(h_a) + b2) fused pool
    k_gemm<<<(NN + 63) / 64, 256, 0, stream>>>(h_b, W2, h_a);
    k_agg<true><<<(NN + 3) / 4, 256, 0, stream>>>(h_a, offsets, counts, csr_row, csr_norm,
                                                  dinv, b2, batch, pooled);
    // FC + log_softmax
    k_fc<<<NG, 64, 0, stream>>>(pooled, Wfc, bfc, out);
}

// Round 2
// 688.621 us; speedup vs baseline: 1.0715x; 1.0715x over previous
//
#include <hip/hip_runtime.h>
#include <hip/hip_bf16.h>

#define NN 50000
#define NE 1600000
#define FEAT 128
#define NG 128
#define NC 10

constexpr int SCAN_BLOCKS = (NN + 255) / 256; // 196

// ---------------- bf16 helpers (manual, RNE) ----------------
__device__ __forceinline__ float bflo(unsigned u) { return __uint_as_float(u << 16); }
__device__ __forceinline__ float bfhi(unsigned u) { return __uint_as_float(u & 0xffff0000u); }
__device__ __forceinline__ unsigned packbf(float a, float b) {
    unsigned ua = __float_as_uint(a), ub = __float_as_uint(b);
    ua += 0x7fffu + ((ua >> 16) & 1u);
    ub += 0x7fffu + ((ub >> 16) & 1u);
    return (ua >> 16) | (ub & 0xffff0000u);
}

// ---------------- degree + count ----------------
__global__ void k_deg_count(const int* __restrict__ col, const float* __restrict__ ew,
                            float* __restrict__ deg, int* __restrict__ counts) {
    int e = blockIdx.x * blockDim.x + threadIdx.x;
    if (e < NE) {
        int c = col[e];
        atomicAdd(&deg[c], ew[e]);
        atomicAdd(&counts[c], 1);
    }
}

__global__ void k_dinv(const float* __restrict__ deg, float* __restrict__ dinv) {
    int n = blockIdx.x * blockDim.x + threadIdx.x;
    if (n < NN) dinv[n] = rsqrtf(deg[n] + 1.0f); // +1 = self-loop weight; always > 0
}

// ---------------- exclusive scan of counts ----------------
__global__ void k_scanA(const int* __restrict__ counts, int* __restrict__ offsets,
                        int* __restrict__ blockSums) {
    __shared__ int tmp[256];
    int i = blockIdx.x * 256 + threadIdx.x;
    int v = (i < NN) ? counts[i] : 0;
    tmp[threadIdx.x] = v;
    __syncthreads();
    for (int off = 1; off < 256; off <<= 1) {
        int t = (threadIdx.x >= off) ? tmp[threadIdx.x - off] : 0;
        __syncthreads();
        tmp[threadIdx.x] += t;
        __syncthreads();
    }
    if (i < NN) offsets[i] = tmp[threadIdx.x] - v;
    if (threadIdx.x == 255) blockSums[blockIdx.x] = tmp[255];
}

__global__ void k_scanB(int* __restrict__ blockSums) {
    __shared__ int tmp[256];
    int t = threadIdx.x;
    int v = (t < SCAN_BLOCKS) ? blockSums[t] : 0;
    tmp[t] = v;
    __syncthreads();
    for (int off = 1; off < 256; off <<= 1) {
        int u = (t >= off) ? tmp[t - off] : 0;
        __syncthreads();
        tmp[t] += u;
        __syncthreads();
    }
    if (t < SCAN_BLOCKS) blockSums[t] = tmp[t] - v;
}

__global__ void k_scanC(int* __restrict__ offsets, const int* __restrict__ blockSums,
                        int* __restrict__ cursor) {
    int i = blockIdx.x * 256 + threadIdx.x;
    if (i < NN) {
        int o = offsets[i] + blockSums[blockIdx.x];
        offsets[i] = o;
        cursor[i] = o;
    }
}

// ---------------- CSR fill: packed {row, norm} ----------------
__global__ void k_fill(const int* __restrict__ row, const int* __restrict__ col,
                       const float* __restrict__ ew, const float* __restrict__ dinv,
                       int* __restrict__ cursor, int2* __restrict__ csr) {
    int e = blockIdx.x * blockDim.x + threadIdx.x;
    if (e < NE) {
        int r = row[e], c = col[e];
        float nrm = dinv[r] * ew[e] * dinv[c];
        int pos = atomicAdd(&cursor[c], 1);
        csr[pos] = make_int2(r, __float_as_int(nrm));
    }
}

// ---------------- GEMM: C_bf16[NN x 128] = A[NN x 128] @ W_f32[128 x 128] ----------------
// TIN: float (layer 1 reads x) or unsigned short (bf16, layer 2 reads h)
template <typename TIN>
__global__ __launch_bounds__(256) void k_gemm(const TIN* __restrict__ A,
                                              const float* __restrict__ W,
                                              unsigned short* __restrict__ C) {
    __shared__ float As[64][33];
    __shared__ float Ws[32][128];
    const int row0 = blockIdx.x * 64;
    const int t = threadIdx.x;
    const int c4 = (t & 31) * 4;
    const int rg = t >> 5;
    float4 acc[8];
#pragma unroll
    for (int i = 0; i < 8; ++i) acc[i] = make_float4(0.f, 0.f, 0.f, 0.f);

    for (int k0 = 0; k0 < 128; k0 += 32) {
        if constexpr (sizeof(TIN) == 4) {
            // fp32 A panel: 64 rows x 32 k
#pragma unroll
            for (int l = 0; l < 2; ++l) {
                int q = t + l * 256;
                int r = q >> 3, kk4 = (q & 7) * 4;
                int grow = row0 + r;
                float4 v = make_float4(0.f, 0.f, 0.f, 0.f);
                if (grow < NN) v = *(const float4*)((const float*)A + (size_t)grow * 128 + k0 + kk4);
                As[r][kk4] = v.x; As[r][kk4 + 1] = v.y; As[r][kk4 + 2] = v.z; As[r][kk4 + 3] = v.w;
            }
        } else {
            // bf16 A panel: one uint4 (8 bf16) per thread
            int r = t >> 2, kk8 = (t & 3) * 8;
            int grow = row0 + r;
            uint4 v = make_uint4(0u, 0u, 0u, 0u);
            if (grow < NN)
                v = *(const uint4*)((const unsigned short*)A + (size_t)grow * 128 + k0 + kk8);
            As[r][kk8 + 0] = bflo(v.x); As[r][kk8 + 1] = bfhi(v.x);
            As[r][kk8 + 2] = bflo(v.y); As[r][kk8 + 3] = bfhi(v.y);
            As[r][kk8 + 4] = bflo(v.z); As[r][kk8 + 5] = bfhi(v.z);
            As[r][kk8 + 6] = bflo(v.w); As[r][kk8 + 7] = bfhi(v.w);
        }
        // W panel: 32 k x 128 cols
#pragma unroll
        for (int l = 0; l < 4; ++l) {
            int q = t + l * 256;
            int kk = q >> 5, cc4 = (q & 31) * 4;
            *(float4*)(&Ws[kk][cc4]) = *(const float4*)(W + (size_t)(k0 + kk) * 128 + cc4);
        }
        __syncthreads();
#pragma unroll
        for (int kk = 0; kk < 32; ++kk) {
            float4 w4 = *(const float4*)(&Ws[kk][c4]);
#pragma unroll
            for (int i = 0; i < 8; ++i) {
                float a = As[rg + 8 * i][kk];
                acc[i].x += a * w4.x;
                acc[i].y += a * w4.y;
                acc[i].z += a * w4.z;
                acc[i].w += a * w4.w;
            }
        }
        __syncthreads();
    }
#pragma unroll
    for (int i = 0; i < 8; ++i) {
        int grow = row0 + rg + 8 * i;
        if (grow < NN) {
            unsigned u0 = packbf(acc[i].x, acc[i].y);
            unsigned u1 = packbf(acc[i].z, acc[i].w);
            *(uint2*)(C + (size_t)grow * 128 + c4) = make_uint2(u0, u1);
        }
    }
}

// ---------------- pull aggregation, bf16 h, half-wave edge split ----------------
// wave per node; lanes 0-31 process even edges, 32-63 odd edges; each feature-lane
// fl = lane&31 owns feats [fl*4, fl*4+4). Combine halves via shfl_xor(32).
template <bool POOL>
__global__ __launch_bounds__(256) void k_agg(const unsigned short* __restrict__ h,
                                             const int* __restrict__ offsets,
                                             const int* __restrict__ counts,
                                             const int2* __restrict__ csr,
                                             const float* __restrict__ dinv,
                                             const float* __restrict__ bias,
                                             const int* __restrict__ batch,
                                             float* __restrict__ outf,
                                             unsigned short* __restrict__ outb) {
    const int node = blockIdx.x * 4 + (threadIdx.x >> 6);
    if (node >= NN) return;
    const int lane = threadIdx.x & 63;
    const int half = lane >> 5;
    const int fl = lane & 31;

    const int start = offsets[node];
    const int cnt = counts[node];
    const int2* ep = csr + start;
    const uint2* hb = (const uint2*)h;

    float a0 = 0.f, a1 = 0.f, a2 = 0.f, a3 = 0.f;

    const int n8 = cnt >> 3;
    for (int i = 0; i < n8; ++i) {
        const int base = i * 8 + half;
        int2 e0 = ep[base];
        int2 e1 = ep[base + 2];
        int2 e2 = ep[base + 4];
        int2 e3 = ep[base + 6];
        uint2 v0 = hb[(size_t)e0.x * 32 + fl];
        uint2 v1 = hb[(size_t)e1.x * 32 + fl];
        uint2 v2 = hb[(size_t)e2.x * 32 + fl];
        uint2 v3 = hb[(size_t)e3.x * 32 + fl];
        float n0 = __int_as_float(e0.y), n1 = __int_as_float(e1.y);
        float n2 = __int_as_float(e2.y), n3 = __int_as_float(e3.y);
        a0 += bflo(v0.x) * n0; a1 += bfhi(v0.x) * n0; a2 += bflo(v0.y) * n0; a3 += bfhi(v0.y) * n0;
        a0 += bflo(v1.x) * n1; a1 += bfhi(v1.x) * n1; a2 += bflo(v1.y) * n1; a3 += bfhi(v1.y) * n1;
        a0 += bflo(v2.x) * n2; a1 += bfhi(v2.x) * n2; a2 += bflo(v2.y) * n2; a3 += bfhi(v2.y) * n2;
        a0 += bflo(v3.x) * n3; a1 += bfhi(v3.x) * n3; a2 += bflo(v3.y) * n3; a3 += bfhi(v3.y) * n3;
    }
    for (int jj = n8 * 8; jj < cnt; jj += 2) {
        int idx = jj + half;
        bool valid = idx < cnt;
        int2 e = ep[valid ? idx : cnt - 1];
        float nw = valid ? __int_as_float(e.y) : 0.f;
        uint2 v = hb[(size_t)e.x * 32 + fl];
        a0 += bflo(v.x) * nw; a1 += bfhi(v.x) * nw;
        a2 += bflo(v.y) * nw; a3 += bfhi(v.y) * nw;
    }

    a0 += __shfl_xor(a0, 32);
    a1 += __shfl_xor(a1, 32);
    a2 += __shfl_xor(a2, 32);
    a3 += __shfl_xor(a3, 32);

    if (half == 0) {
        float di = dinv[node];
        float sn = di * di;
        uint2 sv = hb[(size_t)node * 32 + fl];
        a0 += bflo(sv.x) * sn; a1 += bfhi(sv.x) * sn;
        a2 += bflo(sv.y) * sn; a3 += bfhi(sv.y) * sn;
        float4 b4 = *(const float4*)(bias + fl * 4);
        a0 = fmaxf(a0 + b4.x, 0.f);
        a1 = fmaxf(a1 + b4.y, 0.f);
        a2 = fmaxf(a2 + b4.z, 0.f);
        a3 = fmaxf(a3 + b4.w, 0.f);
        if (POOL) {
            int g = batch[node];
            float* dst = outf + (size_t)g * 128 + fl * 4;
            atomicAdd(dst + 0, a0);
            atomicAdd(dst + 1, a1);
            atomicAdd(dst + 2, a2);
            atomicAdd(dst + 3, a3);
        } else {
            unsigned u0 = packbf(a0, a1), u1 = packbf(a2, a3);
            *(uint2*)(outb + (size_t)node * 128 + fl * 4) = make_uint2(u0, u1);
        }
    }
}

// ---------------- FC + log_softmax: one wave per graph ----------------
__global__ __launch_bounds__(64) void k_fc(const float* __restrict__ pooled,
                                           const float* __restrict__ Wfc,
                                           const float* __restrict__ bfc,
                                           float* __restrict__ out) {
    const int g = blockIdx.x;
    const int lane = threadIdx.x;
    float p0 = pooled[(size_t)g * 128 + lane];
    float p1 = pooled[(size_t)g * 128 + 64 + lane];
    float logits[NC];
#pragma unroll
    for (int c = 0; c < NC; ++c) {
        float v = p0 * Wfc[lane * NC + c] + p1 * Wfc[(64 + lane) * NC + c];
#pragma unroll
        for (int off = 32; off > 0; off >>= 1) v += __shfl_down(v, off);
        logits[c] = v;
    }
    if (lane == 0) {
        float mx = -1e30f;
#pragma unroll
        for (int c = 0; c < NC; ++c) { logits[c] += bfc[c]; mx = fmaxf(mx, logits[c]); }
        float s = 0.f;
#pragma unroll
        for (int c = 0; c < NC; ++c) s += expf(logits[c] - mx);
        float lse = mx + logf(s);
#pragma unroll
        for (int c = 0; c < NC; ++c) out[(size_t)g * NC + c] = logits[c] - lse;
    }
}

extern "C" void kernel_launch(void* const* d_in, const int* in_sizes, int n_in,
                              void* d_out, int out_size, void* d_ws, size_t ws_size,
                              hipStream_t stream) {
    const float* x         = (const float*)d_in[0];
    const int*   edge_index= (const int*)d_in[1];
    const int*   batch     = (const int*)d_in[2];
    const float* edge_mask = (const float*)d_in[3];
    const float* W1        = (const float*)d_in[4];
    const float* b1        = (const float*)d_in[5];
    const float* W2        = (const float*)d_in[6];
    const float* b2        = (const float*)d_in[7];
    const float* Wfc       = (const float*)d_in[8];
    const float* bfc       = (const float*)d_in[9];
    float* out = (float*)d_out;

    const int* row = edge_index;        // edge_index[0]
    const int* col = edge_index + NE;   // edge_index[1]

    char* ws = (char*)d_ws;
    size_t off = 0;
    auto alloc = [&](size_t bytes) -> void* {
        off = (off + 255) & ~(size_t)255;
        void* p = ws + off;
        off += bytes;
        return p;
    };
    float* deg      = (float*)alloc((size_t)NN * 4);
    int*   counts   = (int*)  alloc((size_t)NN * 4);
    int*   offsets  = (int*)  alloc((size_t)NN * 4);
    int*   cursor   = (int*)  alloc((size_t)NN * 4);
    int*   blockSums= (int*)  alloc(256 * 4);
    float* dinv     = (float*)alloc((size_t)NN * 4);
    int2*  csr      = (int2*) alloc((size_t)NE * 8);
    unsigned short* h1 = (unsigned short*)alloc((size_t)NN * FEAT * 2); // bf16
    unsigned short* h2 = (unsigned short*)alloc((size_t)NN * FEAT * 2); // bf16
    float* pooled   = (float*)alloc((size_t)NG * FEAT * 4);

    hipMemsetAsync(deg, 0, (size_t)NN * 4, stream);
    hipMemsetAsync(counts, 0, (size_t)NN * 4, stream);
    hipMemsetAsync(pooled, 0, (size_t)NG * FEAT * 4, stream);

    k_deg_count<<<(NE + 255) / 256, 256, 0, stream>>>(col, edge_mask, deg, counts);
    k_dinv<<<(NN + 255) / 256, 256, 0, stream>>>(deg, dinv);
    k_scanA<<<SCAN_BLOCKS, 256, 0, stream>>>(counts, offsets, blockSums);
    k_scanB<<<1, 256, 0, stream>>>(blockSums);
    k_scanC<<<SCAN_BLOCKS, 256, 0, stream>>>(offsets, blockSums, cursor);
    k_fill<<<(NE + 255) / 256, 256, 0, stream>>>(row, col, edge_mask, dinv, cursor, csr);

    // layer 1: h1 = x @ W1 (bf16) ; h2 = relu(agg(h1) + b1) (bf16)
    k_gemm<float><<<(NN + 63) / 64, 256, 0, stream>>>(x, W1, h1);
    k_agg<false><<<(NN + 3) / 4, 256, 0, stream>>>(h1, offsets, counts, csr, dinv, b1,
                                                   nullptr, nullptr, h2);
    // layer 2: h1 = h2 @ W2 (bf16) ; pooled += relu(agg(h1) + b2)
    k_gemm<unsigned short><<<(NN + 63) / 64, 256, 0, stream>>>(h2, W2, h1);
    k_agg<true><<<(NN + 3) / 4, 256, 0, stream>>>(h1, offsets, counts, csr, dinv, b2,
                                                  batch, pooled, nullptr);
    // FC + log_softmax
    k_fc<<<NG, 64, 0, stream>>>(pooled, Wfc, bfc, out);
}

// Round 4
// 601.841 us; speedup vs baseline: 1.2260x; 1.1442x over previous
//
#include <hip/hip_runtime.h>
#include <hip/hip_bf16.h>

#define NN 50000
#define NE 1600000
#define FEAT 128
#define NG 128
#define NC 10

constexpr int SCAN_BLOCKS = (NN + 255) / 256; // 196

typedef unsigned int u32x4 __attribute__((ext_vector_type(4)));

// ---------------- bf16 helpers (manual, RNE) ----------------
__device__ __forceinline__ float bflo(unsigned u) { return __uint_as_float(u << 16); }
__device__ __forceinline__ float bfhi(unsigned u) { return __uint_as_float(u & 0xffff0000u); }
__device__ __forceinline__ float bfs(unsigned short u) { return __uint_as_float(((unsigned)u) << 16); }
__device__ __forceinline__ unsigned packbf(float a, float b) {
    unsigned ua = __float_as_uint(a), ub = __float_as_uint(b);
    ua += 0x7fffu + ((ua >> 16) & 1u);
    ub += 0x7fffu + ((ub >> 16) & 1u);
    return (ua >> 16) | (ub & 0xffff0000u);
}

// ---------------- degree + count ----------------
__global__ void k_deg_count(const int* __restrict__ col, const float* __restrict__ ew,
                            float* __restrict__ deg, int* __restrict__ counts) {
    int e = blockIdx.x * blockDim.x + threadIdx.x;
    if (e < NE) {
        int c = col[e];
        atomicAdd(&deg[c], ew[e]);
        atomicAdd(&counts[c], 1);
    }
}

__global__ void k_dinv(const float* __restrict__ deg, float* __restrict__ dinv) {
    int n = blockIdx.x * blockDim.x + threadIdx.x;
    if (n < NN) dinv[n] = rsqrtf(deg[n] + 1.0f); // +1 = self-loop weight; always > 0
}

// ---------------- exclusive scan of counts ----------------
__global__ void k_scanA(const int* __restrict__ counts, int* __restrict__ offsets,
                        int* __restrict__ blockSums) {
    __shared__ int tmp[256];
    int i = blockIdx.x * 256 + threadIdx.x;
    int v = (i < NN) ? counts[i] : 0;
    tmp[threadIdx.x] = v;
    __syncthreads();
    for (int off = 1; off < 256; off <<= 1) {
        int t = (threadIdx.x >= off) ? tmp[threadIdx.x - off] : 0;
        __syncthreads();
        tmp[threadIdx.x] += t;
        __syncthreads();
    }
    if (i < NN) offsets[i] = tmp[threadIdx.x] - v;
    if (threadIdx.x == 255) blockSums[blockIdx.x] = tmp[255];
}

__global__ void k_scanB(int* __restrict__ blockSums) {
    __shared__ int tmp[256];
    int t = threadIdx.x;
    int v = (t < SCAN_BLOCKS) ? blockSums[t] : 0;
    tmp[t] = v;
    __syncthreads();
    for (int off = 1; off < 256; off <<= 1) {
        int u = (t >= off) ? tmp[t - off] : 0;
        __syncthreads();
        tmp[t] += u;
        __syncthreads();
    }
    if (t < SCAN_BLOCKS) blockSums[t] = tmp[t] - v;
}

__global__ void k_scanC(int* __restrict__ offsets, const int* __restrict__ blockSums,
                        int* __restrict__ cursor) {
    int i = blockIdx.x * 256 + threadIdx.x;
    if (i < NN) {
        int o = offsets[i] + blockSums[blockIdx.x];
        offsets[i] = o;
        cursor[i] = o;
    }
}

// ---------------- CSR fill: packed {row, ew} (dinv factored out) ----------------
__global__ void k_fill(const int* __restrict__ row, const int* __restrict__ col,
                       const float* __restrict__ ew, int* __restrict__ cursor,
                       long long* __restrict__ csr) {
    int e = blockIdx.x * blockDim.x + threadIdx.x;
    if (e < NE) {
        int r = row[e];
        float w = ew[e];
        int pos = atomicAdd(&cursor[col[e]], 1);
        long long v = (long long)(unsigned)r | ((long long)__float_as_int(w) << 32);
        __builtin_nontemporal_store(v, csr + pos);
    }
}

// ---------------- GEMM: C_bf16[NN x 128] = dinv[row] * (A[NN x 128] @ W[128 x 128]) ----
template <typename TIN>
__global__ __launch_bounds__(256) void k_gemm(const TIN* __restrict__ A,
                                              const float* __restrict__ W,
                                              const float* __restrict__ dinv,
                                              unsigned short* __restrict__ C) {
    __shared__ float As[64][33];
    __shared__ float Ws[32][128];
    const int row0 = blockIdx.x * 64;
    const int t = threadIdx.x;
    const int c4 = (t & 31) * 4;
    const int rg = t >> 5;
    float4 acc[8];
#pragma unroll
    for (int i = 0; i < 8; ++i) acc[i] = make_float4(0.f, 0.f, 0.f, 0.f);

    for (int k0 = 0; k0 < 128; k0 += 32) {
        if constexpr (sizeof(TIN) == 4) {
#pragma unroll
            for (int l = 0; l < 2; ++l) {
                int q = t + l * 256;
                int r = q >> 3, kk4 = (q & 7) * 4;
                int grow = row0 + r;
                float4 v = make_float4(0.f, 0.f, 0.f, 0.f);
                if (grow < NN) v = *(const float4*)((const float*)A + (size_t)grow * 128 + k0 + kk4);
                As[r][kk4] = v.x; As[r][kk4 + 1] = v.y; As[r][kk4 + 2] = v.z; As[r][kk4 + 3] = v.w;
            }
        } else {
            int r = t >> 2, kk8 = (t & 3) * 8;
            int grow = row0 + r;
            uint4 v = make_uint4(0u, 0u, 0u, 0u);
            if (grow < NN)
                v = *(const uint4*)((const unsigned short*)A + (size_t)grow * 128 + k0 + kk8);
            As[r][kk8 + 0] = bflo(v.x); As[r][kk8 + 1] = bfhi(v.x);
            As[r][kk8 + 2] = bflo(v.y); As[r][kk8 + 3] = bfhi(v.y);
            As[r][kk8 + 4] = bflo(v.z); As[r][kk8 + 5] = bfhi(v.z);
            As[r][kk8 + 6] = bflo(v.w); As[r][kk8 + 7] = bfhi(v.w);
        }
#pragma unroll
        for (int l = 0; l < 4; ++l) {
            int q = t + l * 256;
            int kk = q >> 5, cc4 = (q & 31) * 4;
            *(float4*)(&Ws[kk][cc4]) = *(const float4*)(W + (size_t)(k0 + kk) * 128 + cc4);
        }
        __syncthreads();
#pragma unroll
        for (int kk = 0; kk < 32; ++kk) {
            float4 w4 = *(const float4*)(&Ws[kk][c4]);
#pragma unroll
            for (int i = 0; i < 8; ++i) {
                float a = As[rg + 8 * i][kk];
                acc[i].x += a * w4.x;
                acc[i].y += a * w4.y;
                acc[i].z += a * w4.z;
                acc[i].w += a * w4.w;
            }
        }
        __syncthreads();
    }
#pragma unroll
    for (int i = 0; i < 8; ++i) {
        int grow = row0 + rg + 8 * i;
        if (grow < NN) {
            float di = dinv[grow];
            unsigned u0 = packbf(acc[i].x * di, acc[i].y * di);
            unsigned u1 = packbf(acc[i].z * di, acc[i].w * di);
            *(uint2*)(C + (size_t)grow * 128 + c4) = make_uint2(u0, u1);
        }
    }
}

// ---------------- pull aggregation: quarter-wave (16 lanes = one 256B row) ----------
// out[n] = relu( b + dinv[n] * ( sum_e ew_e * hs[row_e] + hs[n] ) ), bf16 out
__global__ __launch_bounds__(256) void k_agg(const unsigned short* __restrict__ hs,
                                             const int* __restrict__ offsets,
                                             const int* __restrict__ counts,
                                             const long long* __restrict__ csr,
                                             const float* __restrict__ dinv,
                                             const float* __restrict__ bias,
                                             unsigned short* __restrict__ outb) {
    const int node = blockIdx.x * 4 + (threadIdx.x >> 6);
    if (node >= NN) return;
    const int lane = threadIdx.x & 63;
    const int qg = lane >> 4;   // quarter-group: which edge of 4
    const int fl = lane & 15;   // feature lane: owns feats [fl*8, fl*8+8)

    const int start = offsets[node];
    const int cnt = counts[node];
    const long long* ep = csr + start;
    const uint4* hb = (const uint4*)hs;

    float a0 = 0.f, a1 = 0.f, a2 = 0.f, a3 = 0.f;
    float a4 = 0.f, a5 = 0.f, a6 = 0.f, a7 = 0.f;

    auto fma8 = [&](uint4 v, float w) {
        a0 += bflo(v.x) * w; a1 += bfhi(v.x) * w;
        a2 += bflo(v.y) * w; a3 += bfhi(v.y) * w;
        a4 += bflo(v.z) * w; a5 += bfhi(v.z) * w;
        a6 += bflo(v.w) * w; a7 += bfhi(v.w) * w;
    };

    const int n16 = cnt >> 4;
    for (int i = 0; i < n16; ++i) {
        const int base = i * 16 + qg;
        long long l0 = __builtin_nontemporal_load(ep + base);
        long long l1 = __builtin_nontemporal_load(ep + base + 4);
        long long l2 = __builtin_nontemporal_load(ep + base + 8);
        long long l3 = __builtin_nontemporal_load(ep + base + 12);
        uint4 v0 = hb[(size_t)(int)l0 * 16 + fl];
        uint4 v1 = hb[(size_t)(int)l1 * 16 + fl];
        uint4 v2 = hb[(size_t)(int)l2 * 16 + fl];
        uint4 v3 = hb[(size_t)(int)l3 * 16 + fl];
        fma8(v0, __int_as_float((int)(l0 >> 32)));
        fma8(v1, __int_as_float((int)(l1 >> 32)));
        fma8(v2, __int_as_float((int)(l2 >> 32)));
        fma8(v3, __int_as_float((int)(l3 >> 32)));
    }
    for (int jj = n16 * 16; jj < cnt; jj += 4) {
        int idx = jj + qg;
        bool valid = idx < cnt;
        long long l = __builtin_nontemporal_load(ep + (valid ? idx : cnt - 1));
        float w = valid ? __int_as_float((int)(l >> 32)) : 0.f;
        uint4 v = hb[(size_t)(int)l * 16 + fl];
        fma8(v, w);
    }

    // combine the 4 quarter-groups
    a0 += __shfl_xor(a0, 16); a0 += __shfl_xor(a0, 32);
    a1 += __shfl_xor(a1, 16); a1 += __shfl_xor(a1, 32);
    a2 += __shfl_xor(a2, 16); a2 += __shfl_xor(a2, 32);
    a3 += __shfl_xor(a3, 16); a3 += __shfl_xor(a3, 32);
    a4 += __shfl_xor(a4, 16); a4 += __shfl_xor(a4, 32);
    a5 += __shfl_xor(a5, 16); a5 += __shfl_xor(a5, 32);
    a6 += __shfl_xor(a6, 16); a6 += __shfl_xor(a6, 32);
    a7 += __shfl_xor(a7, 16); a7 += __shfl_xor(a7, 32);

    if (qg == 0) {
        uint4 sv = hb[(size_t)node * 16 + fl];
        fma8(sv, 1.0f);                        // self-loop term: + hs[node]
        float di = dinv[node];
        float4 b0 = *(const float4*)(bias + fl * 8);
        float4 b1 = *(const float4*)(bias + fl * 8 + 4);
        a0 = fmaxf(di * a0 + b0.x, 0.f);
        a1 = fmaxf(di * a1 + b0.y, 0.f);
        a2 = fmaxf(di * a2 + b0.z, 0.f);
        a3 = fmaxf(di * a3 + b0.w, 0.f);
        a4 = fmaxf(di * a4 + b1.x, 0.f);
        a5 = fmaxf(di * a5 + b1.y, 0.f);
        a6 = fmaxf(di * a6 + b1.z, 0.f);
        a7 = fmaxf(di * a7 + b1.w, 0.f);
        u32x4 o;
        o.x = packbf(a0, a1); o.y = packbf(a2, a3);
        o.z = packbf(a4, a5); o.w = packbf(a6, a7);
        __builtin_nontemporal_store(o, (u32x4*)(outb + (size_t)node * 128 + fl * 8));
    }
}

// ---------------- segmented pooling (batch sorted): one block per graph --------------
__global__ __launch_bounds__(256) void k_pool(const unsigned short* __restrict__ h3,
                                              const int* __restrict__ batch,
                                              float* __restrict__ pooled) {
    __shared__ float sm[256];
    const int g = blockIdx.x;
    const int f = threadIdx.x & 127;
    const int half = threadIdx.x >> 7;
    // lower_bound(g), lower_bound(g+1)
    int lo = 0, hi = NN;
    while (lo < hi) { int m = (lo + hi) >> 1; if (batch[m] < g) lo = m + 1; else hi = m; }
    int s0 = lo;
    hi = NN;
    while (lo < hi) { int m = (lo + hi) >> 1; if (batch[m] < g + 1) lo = m + 1; else hi = m; }
    int e0 = lo;

    float s = 0.f;
    int n = s0 + half;
    for (; n + 8 <= e0; n += 8) {
        s += bfs(h3[(size_t)n * 128 + f]);
        s += bfs(h3[(size_t)(n + 2) * 128 + f]);
        s += bfs(h3[(size_t)(n + 4) * 128 + f]);
        s += bfs(h3[(size_t)(n + 6) * 128 + f]);
    }
    for (; n < e0; n += 2) s += bfs(h3[(size_t)n * 128 + f]);

    sm[threadIdx.x] = s;
    __syncthreads();
    if (half == 0) pooled[(size_t)g * 128 + f] = sm[threadIdx.x] + sm[threadIdx.x + 128];
}

// ---------------- FC + log_softmax: one wave per graph ----------------
__global__ __launch_bounds__(64) void k_fc(const float* __restrict__ pooled,
                                           const float* __restrict__ Wfc,
                                           const float* __restrict__ bfc,
                                           float* __restrict__ out) {
    const int g = blockIdx.x;
    const int lane = threadIdx.x;
    float p0 = pooled[(size_t)g * 128 + lane];
    float p1 = pooled[(size_t)g * 128 + 64 + lane];
    float logits[NC];
#pragma unroll
    for (int c = 0; c < NC; ++c) {
        float v = p0 * Wfc[lane * NC + c] + p1 * Wfc[(64 + lane) * NC + c];
#pragma unroll
        for (int off = 32; off > 0; off >>= 1) v += __shfl_down(v, off);
        logits[c] = v;
    }
    if (lane == 0) {
        float mx = -1e30f;
#pragma unroll
        for (int c = 0; c < NC; ++c) { logits[c] += bfc[c]; mx = fmaxf(mx, logits[c]); }
        float s = 0.f;
#pragma unroll
        for (int c = 0; c < NC; ++c) s += expf(logits[c] - mx);
        float lse = mx + logf(s);
#pragma unroll
        for (int c = 0; c < NC; ++c) out[(size_t)g * NC + c] = logits[c] - lse;
    }
}

extern "C" void kernel_launch(void* const* d_in, const int* in_sizes, int n_in,
                              void* d_out, int out_size, void* d_ws, size_t ws_size,
                              hipStream_t stream) {
    const float* x         = (const float*)d_in[0];
    const int*   edge_index= (const int*)d_in[1];
    const int*   batch     = (const int*)d_in[2];
    const float* edge_mask = (const float*)d_in[3];
    const float* W1        = (const float*)d_in[4];
    const float* b1        = (const float*)d_in[5];
    const float* W2        = (const float*)d_in[6];
    const float* b2        = (const float*)d_in[7];
    const float* Wfc       = (const float*)d_in[8];
    const float* bfc       = (const float*)d_in[9];
    float* out = (float*)d_out;

    const int* row = edge_index;        // edge_index[0]
    const int* col = edge_index + NE;   // edge_index[1]

    char* ws = (char*)d_ws;
    size_t off = 0;
    auto alloc = [&](size_t bytes) -> void* {
        off = (off + 255) & ~(size_t)255;
        void* p = ws + off;
        off += bytes;
        return p;
    };
    float* deg      = (float*)alloc((size_t)NN * 4);
    int*   counts   = (int*)  alloc((size_t)NN * 4);
    int*   offsets  = (int*)  alloc((size_t)NN * 4);
    int*   cursor   = (int*)  alloc((size_t)NN * 4);
    int*   blockSums= (int*)  alloc(256 * 4);
    float* dinv     = (float*)alloc((size_t)NN * 4);
    long long* csr  = (long long*)alloc((size_t)NE * 8);
    unsigned short* hs1 = (unsigned short*)alloc((size_t)NN * FEAT * 2); // scaled bf16
    unsigned short* h2  = (unsigned short*)alloc((size_t)NN * FEAT * 2); // relu out bf16
    unsigned short* h3  = (unsigned short*)alloc((size_t)NN * FEAT * 2); // layer2 out bf16
    float* pooled   = (float*)alloc((size_t)NG * FEAT * 4);

    hipMemsetAsync(deg, 0, (size_t)NN * 4, stream);
    hipMemsetAsync(counts, 0, (size_t)NN * 4, stream);

    k_deg_count<<<(NE + 255) / 256, 256, 0, stream>>>(col, edge_mask, deg, counts);
    k_dinv<<<(NN + 255) / 256, 256, 0, stream>>>(deg, dinv);
    k_scanA<<<SCAN_BLOCKS, 256, 0, stream>>>(counts, offsets, blockSums);
    k_scanB<<<1, 256, 0, stream>>>(blockSums);
    k_scanC<<<SCAN_BLOCKS, 256, 0, stream>>>(offsets, blockSums, cursor);
    k_fill<<<(NE + 255) / 256, 256, 0, stream>>>(row, col, edge_mask, cursor, csr);

    // layer 1: hs1 = dinv * (x @ W1); h2 = relu(b1 + dinv*(sum ew*hs1 + hs1))
    k_gemm<float><<<(NN + 63) / 64, 256, 0, stream>>>(x, W1, dinv, hs1);
    k_agg<<<(NN + 3) / 4, 256, 0, stream>>>(hs1, offsets, counts, csr, dinv, b1, h2);
    // layer 2: hs1 <- dinv * (h2 @ W2)
    k_gemm<unsigned short><<<(NN + 63) / 64, 256, 0, stream>>>(h2, W2, dinv, hs1);
    k_agg<<<(NN + 3) / 4, 256, 0, stream>>>(hs1, offsets, counts, csr, dinv, b2, h3);
    // pool + FC
    k_pool<<<NG, 256, 0, stream>>>(h3, batch, pooled);
    k_fc<<<NG, 64, 0, stream>>>(pooled, Wfc, bfc, out);
}